// Round 6
// baseline (373.707 us; speedup 1.0000x reference)
//
#include <hip/hip_runtime.h>
#include <hip/hip_bf16.h>

// B=8, S=512 -> TOK=4096 tokens, D=1024, F=2048, H=16 heads, O=1.
#define TOK 4096
#define DD  1024
#define FF  2048
#define NH  16

typedef short bf16x8 __attribute__((ext_vector_type(8)));
typedef float f32x4  __attribute__((ext_vector_type(4)));

__device__ __forceinline__ float gelu_f(float x) {
  float u = 0.7978845608028654f * (x + 0.044715f * x * x * x);
  float e = __expf(2.0f * u);
  return 0.5f * x * (2.0f - 2.0f / (e + 1.0f));
}

// fp32 -> bf16 round-to-nearest-even
__device__ __forceinline__ unsigned short f2bf(float f) {
  union { float f; unsigned u; } v; v.f = f;
  unsigned r = v.u + 0x7FFF + ((v.u >> 16) & 1);
  return (unsigned short)(r >> 16);
}
__device__ __forceinline__ unsigned pack2(float a, float b) {
  return (unsigned)f2bf(a) | ((unsigned)f2bf(b) << 16);
}

// ---------------------------------------------------------------------------
// prep_fused: one dispatch, three block ranges.
//   [0, 8192):      W1 pack  (direct strided reads, contiguous writes, NO LDS)
//   [8192, 8448):   Ws pack  (same pattern)
//   [8448, 10496):  X build + routing + out init
// Frag-major chunk c = ((h*128 + NT)*32 + kc2)*64 + lane, elem j:
//   value = W[kc2*32 + (lane>>4)*8 + j][NT*16 + (lane&15)]
// Each pack thread produces an NT-pair (2*ntp, 2*ntp+1): the +16-col second
// read completes the 128B line its first read opened (full line utilization),
// and per instruction lanes form 4 x 64B coalesced segments.
// ---------------------------------------------------------------------------
__global__ __launch_bounds__(256) void prep_fused(
    const int* __restrict__ selfies, const int* __restrict__ tasks,
    const float* __restrict__ values, const int* __restrict__ pmask,
    const float* __restrict__ emb_s, const float* __restrict__ emb_t,
    const float* __restrict__ val_vec, const float* __restrict__ b2,
    const float* __restrict__ Ws, const float* __restrict__ W1,
    unsigned short* __restrict__ Wsp, unsigned short* __restrict__ W1p,
    unsigned short* __restrict__ Xb, int* __restrict__ counts,
    int* __restrict__ lists, float* __restrict__ out) {
  const int tid = threadIdx.x;
  const int bid = blockIdx.x;

  if (bid >= 8448) {
    // ---- X build + routing ----
    int gid = (bid - 8448) * 256 + tid;   // TOK*128 threads
    int kc = (gid & 127) * 8;
    int t  = gid >> 7;
    int sid = selfies[t], tsk = tasks[t];
    if ((gid & 127) == 0) {
      if (tsk > 0) {
        int h = (tsk - 1) & (NH - 1);
        int pos = atomicAdd(&counts[h], 1);
        lists[h * TOK + pos] = t;
        out[t] = b2[h];
      } else {
        out[t] = 0.0f;
      }
    }
    float v = values[t];
    float msk = pmask[t] ? 1.0f : 0.0f;
    const float* ps = emb_s + (size_t)sid * DD + kc;
    const float* pt = emb_t + (size_t)tsk * DD + kc;
    const float* pv = val_vec + kc;
    float r[8];
#pragma unroll
    for (int j = 0; j < 8; j += 4) {
      float4 a = *(const float4*)(ps + j);
      float4 b = *(const float4*)(pt + j);
      float4 c = *(const float4*)(pv + j);
      r[j + 0] = (a.x + b.x + v * c.x) * msk;
      r[j + 1] = (a.y + b.y + v * c.y) * msk;
      r[j + 2] = (a.z + b.z + v * c.z) * msk;
      r[j + 3] = (a.w + b.w + v * c.w) * msk;
    }
    uint4 o;
    o.x = pack2(r[0], r[1]); o.y = pack2(r[2], r[3]);
    o.z = pack2(r[4], r[5]); o.w = pack2(r[6], r[7]);
    *(uint4*)(Xb + (size_t)gid * 8) = o;
    return;
  }

  // ---- weight pack (direct, no LDS) ----
  const float* src0;
  unsigned short *dst0, *dst1;
  int stride;
  if (bid < 8192) {
    int cid = bid * 256 + tid;   // h(16) x ntp(64) x kc2(32) x lane(64)
    int lane = cid & 63, kc2 = (cid >> 6) & 31, ntp = (cid >> 11) & 63, h = cid >> 17;
    int q = lane >> 4, c = lane & 15;
    src0 = W1 + ((size_t)h * DD + kc2 * 32 + q * 8) * FF + ntp * 32 + c;
    size_t c0 = (((size_t)h * 128 + ntp * 2) * 32 + kc2) * 64 + lane;
    dst0 = W1p + c0 * 8;
    dst1 = W1p + (c0 + 32 * 64) * 8;    // NT+1 -> +2048 chunks
    stride = FF;
  } else {
    int cid = (bid - 8192) * 256 + tid; // ntp(32) x kc2(32) x lane(64)
    int lane = cid & 63, kc2 = (cid >> 6) & 31, ntp = cid >> 11;
    int q = lane >> 4, c = lane & 15;
    src0 = Ws + ((size_t)kc2 * 32 + q * 8) * DD + ntp * 32 + c;
    size_t c0 = ((size_t)(ntp * 2) * 32 + kc2) * 64 + lane;
    dst0 = Wsp + c0 * 8;
    dst1 = Wsp + (c0 + 32 * 64) * 8;
    stride = DD;
  }
  float r0[8], r1[8];
#pragma unroll
  for (int j = 0; j < 8; ++j) {
    r0[j] = src0[(size_t)j * stride];
    r1[j] = src0[(size_t)j * stride + 16];
  }
  uint4 o0, o1;
  o0.x = pack2(r0[0], r0[1]); o0.y = pack2(r0[2], r0[3]);
  o0.z = pack2(r0[4], r0[5]); o0.w = pack2(r0[6], r0[7]);
  o1.x = pack2(r1[0], r1[1]); o1.y = pack2(r1[2], r1[3]);
  o1.z = pack2(r1[4], r1[5]); o1.w = pack2(r1[6], r1[7]);
  *(uint4*)dst0 = o0;
  *(uint4*)dst1 = o1;
}

// ---------------------------------------------------------------------------
// Stage 1: shared = gelu(X @ Ws + bs). Barrier-free, A direct from Xb,
// B from frag-major Wsp, depth-1 register prefetch. Block = 4 waves,
// wave = 64m x 64n. grid (64, 4) = 256 blocks = 1/CU.
// ---------------------------------------------------------------------------
__global__ __launch_bounds__(256, 2) void gemm1_mfma(
    const unsigned short* __restrict__ Xb, const unsigned short* __restrict__ Wsp,
    const float* __restrict__ bs, unsigned short* __restrict__ shared_bf) {
  const int tid = threadIdx.x;
  const int lane = tid & 63, w = tid >> 6;
  const int m0 = blockIdx.x * 64;
  const int n0 = blockIdx.y * 256 + w * 64;
  const int q = lane >> 4, c = lane & 15;

  const unsigned short* aP[4];
#pragma unroll
  for (int mt = 0; mt < 4; ++mt)
    aP[mt] = Xb + (size_t)(m0 + mt * 16 + c) * DD + q * 8;

  const unsigned short* bP[4];
#pragma unroll
  for (int t = 0; t < 4; ++t)
    bP[t] = Wsp + (((size_t)(n0 / 16 + t) * 32) * 64 + lane) * 8;

  f32x4 acc[4][4] = {};
  bf16x8 aC[4], bC[4], aN[4], bN[4];

#pragma unroll
  for (int mt = 0; mt < 4; ++mt) aC[mt] = *(const bf16x8*)(aP[mt]);
#pragma unroll
  for (int t = 0; t < 4; ++t) bC[t] = *(const bf16x8*)(bP[t]);

#pragma unroll
  for (int s = 0; s < 32; ++s) {
    if (s < 31) {
#pragma unroll
      for (int mt = 0; mt < 4; ++mt)
        aN[mt] = *(const bf16x8*)(aP[mt] + (s + 1) * 32);
#pragma unroll
      for (int t = 0; t < 4; ++t)
        bN[t] = *(const bf16x8*)(bP[t] + (size_t)(s + 1) * 512);
    }
#pragma unroll
    for (int mt = 0; mt < 4; ++mt)
#pragma unroll
      for (int t = 0; t < 4; ++t)
        acc[mt][t] = __builtin_amdgcn_mfma_f32_16x16x32_bf16(aC[mt], bC[t], acc[mt][t], 0, 0, 0);
#pragma unroll
    for (int mt = 0; mt < 4; ++mt) aC[mt] = aN[mt];
#pragma unroll
    for (int t = 0; t < 4; ++t) bC[t] = bN[t];
  }

  float bsv[4];
#pragma unroll
  for (int t = 0; t < 4; ++t) bsv[t] = bs[n0 + t * 16 + c];
#pragma unroll
  for (int mt = 0; mt < 4; ++mt)
#pragma unroll
    for (int t = 0; t < 4; ++t)
#pragma unroll
      for (int r = 0; r < 4; ++r) {
        int row = m0 + mt * 16 + q * 4 + r;
        int col = n0 + t * 16 + c;
        shared_bf[(size_t)row * DD + col] = f2bf(gelu_f(acc[mt][t][r] + bsv[t]));
      }
}

// ---------------------------------------------------------------------------
// Stage 2: per-head MLP, barrier-free K-loop, wave = 96 tokens x 64 F
// (24 MFMA per 10 loads). Grid 512, XCD-swizzled: all 4 token-tiles of one
// (h,fc) share blockIdx%8 -> same XCD L2 (B slice fetched once per XCD).
// ---------------------------------------------------------------------------
__global__ __launch_bounds__(256, 2) void gemm2_mfma(
    const unsigned short* __restrict__ shared_bf, const unsigned short* __restrict__ W1p,
    const float* __restrict__ b1, const float* __restrict__ W2,
    const int* __restrict__ counts, const int* __restrict__ lists,
    float* __restrict__ out) {
  // Decode: bid = ((g>>3)*4 + tile)*8 + (g&7), g = h*8 + fc, tile in [0,4)
  int bid = blockIdx.x;
  int slot = bid & 7;
  int mid  = bid >> 3;
  int tile = mid & 3;
  int g    = (mid >> 2) * 8 + slot;
  int h    = g >> 3;
  int fc   = g & 7;

  const int nt_h = counts[h];
  const int m0 = tile * 96;
  if (m0 >= nt_h) return;

  __shared__ float red[4][100];

  const int tid = threadIdx.x;
  const int lane = tid & 63, w = tid >> 6;
  const int q = lane >> 4, c = lane & 15;
  const int* lp = lists + h * TOK;

  // A pointers: gathered token rows (clamped; dead rows discarded in epilogue)
  const unsigned short* aP[6];
#pragma unroll
  for (int mt = 0; mt < 6; ++mt) {
    int idx = m0 + mt * 16 + c;
    int tok = lp[idx < nt_h ? idx : nt_h - 1];
    aP[mt] = shared_bf + (size_t)tok * DD + q * 8;
  }

  // B pointers: NT = fc*16 + w*4 + t
  const unsigned short* bP[4];
#pragma unroll
  for (int t = 0; t < 4; ++t)
    bP[t] = W1p + (((size_t)(h * 128 + fc * 16 + w * 4 + t) * 32) * 64 + lane) * 8;

  f32x4 acc[6][4] = {};
  bf16x8 aC[6], bC[4], aN[6], bN[4];

#pragma unroll
  for (int mt = 0; mt < 6; ++mt) aC[mt] = *(const bf16x8*)(aP[mt]);
#pragma unroll
  for (int t = 0; t < 4; ++t) bC[t] = *(const bf16x8*)(bP[t]);

#pragma unroll
  for (int s = 0; s < 32; ++s) {
    if (s < 31) {
#pragma unroll
      for (int mt = 0; mt < 6; ++mt)
        aN[mt] = *(const bf16x8*)(aP[mt] + (s + 1) * 32);
#pragma unroll
      for (int t = 0; t < 4; ++t)
        bN[t] = *(const bf16x8*)(bP[t] + (size_t)(s + 1) * 512);
    }
#pragma unroll
    for (int mt = 0; mt < 6; ++mt)
#pragma unroll
      for (int t = 0; t < 4; ++t)
        acc[mt][t] = __builtin_amdgcn_mfma_f32_16x16x32_bf16(aC[mt], bC[t], acc[mt][t], 0, 0, 0);
#pragma unroll
    for (int mt = 0; mt < 6; ++mt) aC[mt] = aN[mt];
#pragma unroll
    for (int t = 0; t < 4; ++t) bC[t] = bN[t];
  }

  // Epilogue: lane cols n = fc*256 + w*64 + t*16 + c
  const float* b1h = b1 + (size_t)h * FF + fc * 256 + w * 64;
  const float* w2h = W2 + (size_t)h * FF + fc * 256 + w * 64;
  float b1v[4], w2v[4];
#pragma unroll
  for (int t = 0; t < 4; ++t) { b1v[t] = b1h[t * 16 + c]; w2v[t] = w2h[t * 16 + c]; }

#pragma unroll
  for (int mt = 0; mt < 6; ++mt)
#pragma unroll
    for (int r = 0; r < 4; ++r) {
      float s = 0.0f;
#pragma unroll
      for (int t = 0; t < 4; ++t)
        s += gelu_f(acc[mt][t][r] + b1v[t]) * w2v[t];
      s += __shfl_xor(s, 1);
      s += __shfl_xor(s, 2);
      s += __shfl_xor(s, 4);
      s += __shfl_xor(s, 8);
      if (c == 0) red[w][mt * 16 + q * 4 + r] = s;
    }
  __syncthreads();

  if (tid < 96) {
    int i = m0 + tid;
    if (i < nt_h) {
      float s = red[0][tid] + red[1][tid] + red[2][tid] + red[3][tid];
      atomicAdd(&out[lp[i]], s);
    }
  }
}

// ---------------------------------------------------------------------------
extern "C" void kernel_launch(void* const* d_in, const int* in_sizes, int n_in,
                              void* d_out, int out_size, void* d_ws, size_t ws_size,
                              hipStream_t stream) {
  const int*   selfies = (const int*)d_in[0];
  const int*   tasks   = (const int*)d_in[1];
  const float* values  = (const float*)d_in[2];
  const int*   pmask   = (const int*)d_in[3];
  const float* emb_s   = (const float*)d_in[4];
  const float* emb_t   = (const float*)d_in[5];
  const float* val_vec = (const float*)d_in[6];
  const float* Ws      = (const float*)d_in[7];
  const float* bs      = (const float*)d_in[8];
  const float* W1      = (const float*)d_in[9];
  const float* b1      = (const float*)d_in[10];
  const float* W2      = (const float*)d_in[11];
  const float* b2      = (const float*)d_in[12];
  float* out = (float*)d_out;

  // Workspace layout (256-B aligned):
  //   Xb        bf16 [4096][1024]   8 MB   @ 0
  //   shared_bf bf16 [4096][1024]   8 MB   @ 8 MB
  //   Wsp       bf16 frag-major     2 MB   @ 16 MB
  //   W1p       bf16 frag-major    64 MB   @ 18 MB
  //   counts    int[16]                    @ 82 MB
  //   lists     int[16*4096]               @ 82 MB + 256
  char* ws = (char*)d_ws;
  unsigned short* Xb        = (unsigned short*)ws;
  unsigned short* shared_bf = (unsigned short*)(ws + (8u << 20));
  unsigned short* Wsp       = (unsigned short*)(ws + (16u << 20));
  unsigned short* W1p       = (unsigned short*)(ws + (18u << 20));
  int* counts = (int*)(ws + (82u << 20));
  int* lists  = (int*)(ws + (82u << 20) + 256);

  hipMemsetAsync(counts, 0, NH * sizeof(int), stream);
  // 8192 W1-pack blocks + 256 Ws-pack blocks + 2048 X-build blocks
  prep_fused<<<8192 + 256 + 2048, 256, 0, stream>>>(selfies, tasks, values, pmask,
                                                    emb_s, emb_t, val_vec, b2,
                                                    Ws, W1, Wsp, W1p,
                                                    Xb, counts, lists, out);
  gemm1_mfma<<<dim3(TOK / 64, DD / 256), 256, 0, stream>>>(Xb, Wsp, bs, shared_bf);
  gemm2_mfma<<<512, 256, 0, stream>>>(shared_bf, W1p, b1, W2, counts, lists, out);
}